// Round 7
// baseline (111.505 us; speedup 1.0000x reference)
//
#include <hip/hip_runtime.h>

// out[b] = sum_h (x @ W^T)[b,h] * 1.0  ==  dot(x[b,:], colsum_h(W))
// Phase 1: partial column sums of W. 1024 blocks (4/CU, 16 waves/CU).
// Phase 2: wide reduce of 256 partials -> wsum (64 blocks).
// Phase 3: matvec (R4 structure): 8192 blocks, LDS wsum, ONE row per wave.
//          A/B this round: plain (non-NT) loads on the x stream.

#define BATCH   32768
#define HIDDEN  4096
#define INDIM   4096
#define ROWCHUNKS 256
#define ROWS_PER_CHUNK (HIDDEN / ROWCHUNKS)   // 16

typedef float f32x4 __attribute__((ext_vector_type(4)));

// ---------------------------------------------------------------------------
// Kernel 1: partial column sums. grid (4, 256), block 256 -> 1024 blocks.
__global__ void __launch_bounds__(256)
colsum_partial_kernel(const float* __restrict__ W, float* __restrict__ partial) {
    const int col4 = blockIdx.x * 256 + threadIdx.x;      // 0..1023
    const int row0 = blockIdx.y * ROWS_PER_CHUNK;
    const f32x4* Wv = reinterpret_cast<const f32x4*>(W);
    f32x4 acc = {0.f, 0.f, 0.f, 0.f};
#pragma unroll 16
    for (int r = 0; r < ROWS_PER_CHUNK; ++r) {
        f32x4 v = Wv[(size_t)(row0 + r) * (INDIM / 4) + col4];
        acc += v;
    }
    reinterpret_cast<f32x4*>(partial)[(size_t)blockIdx.y * (INDIM / 4) + col4] = acc;
}

// ---------------------------------------------------------------------------
// Kernel 2: wide reduce: 64 blocks x 256 threads, block owns 64 columns.
// Wave w sums chunks [w*64, (w+1)*64); 1 KiB LDS cross-wave reduce.
__global__ void __launch_bounds__(256)
colsum_final_kernel(const float* __restrict__ partial, float* __restrict__ wsum) {
    __shared__ float red[4][64];
    const int t    = threadIdx.x;
    const int lane = t & 63;
    const int wave = t >> 6;
    const int col  = blockIdx.x * 64 + lane;
    float acc = 0.f;
#pragma unroll 8
    for (int p = 0; p < ROWCHUNKS / 4; ++p)               // 64 chunks per wave
        acc += partial[(size_t)(wave * (ROWCHUNKS / 4) + p) * INDIM + col];
    red[wave][lane] = acc;
    __syncthreads();
    if (wave == 0)
        wsum[col] = (red[0][lane] + red[1][lane]) + (red[2][lane] + red[3][lane]);
}

// ---------------------------------------------------------------------------
// Kernel 3 (R4 structure): one wave per row, 4 rows/block, 8192 blocks.
// wsum staged in LDS; hot loop issues only x loads. Plain loads (NT A/B).
__global__ void __launch_bounds__(256)
matvec_kernel(const float* __restrict__ x, const float* __restrict__ wsum,
              float* __restrict__ out) {
    __shared__ f32x4 wlds[INDIM / 4];                     // 16 KiB
    const int tid = threadIdx.x;
    const f32x4* wv = reinterpret_cast<const f32x4*>(wsum);
#pragma unroll
    for (int j = 0; j < 4; ++j)
        wlds[j * 256 + tid] = wv[j * 256 + tid];
    __syncthreads();

    const int row  = (blockIdx.x * 256 + tid) >> 6;       // global wave id
    const int lane = tid & 63;
    const f32x4* xv = reinterpret_cast<const f32x4*>(x) + (size_t)row * (INDIM / 4);

    float acc = 0.f;
#pragma unroll
    for (int k = 0; k < INDIM / 4 / 64; ++k) {            // 16 steps
        const int idx = k * 64 + lane;
        f32x4 xr = xv[idx];                               // plain load this round
        f32x4 wr = wlds[idx];
        acc += xr.x * wr.x + xr.y * wr.y + xr.z * wr.z + xr.w * wr.w;
    }

#pragma unroll
    for (int off = 32; off > 0; off >>= 1)
        acc += __shfl_down(acc, off, 64);

    if (lane == 0)
        out[row] = acc * 1.0f;   // COMBINED_SCALE = 2.0/2.0
}

// ---------------------------------------------------------------------------
extern "C" void kernel_launch(void* const* d_in, const int* in_sizes, int n_in,
                              void* d_out, int out_size, void* d_ws, size_t ws_size,
                              hipStream_t stream) {
    const float* x = (const float*)d_in[0];        // (32768, 4096)
    const float* W = (const float*)d_in[1];        // (4096, 4096)
    float* out = (float*)d_out;                    // 32768 floats

    float* partial = (float*)d_ws;                               // 4 MiB
    float* wsum    = partial + (size_t)ROWCHUNKS * INDIM;        // 16 KiB

    colsum_partial_kernel<<<dim3(INDIM / 4 / 256, ROWCHUNKS), 256, 0, stream>>>(W, partial);
    colsum_final_kernel<<<dim3(INDIM / 64), 256, 0, stream>>>(partial, wsum);
    matvec_kernel<<<dim3(BATCH / 4), 256, 0, stream>>>(x, wsum, out);
}

// Round 8
// 98.563 us; speedup vs baseline: 1.1313x; 1.1313x over previous
//
#include <hip/hip_runtime.h>

// out[b] = sum_h (x @ W^T)[b,h] * 1.0  ==  dot(x[b,:], colsum_h(W))
// R4 structure exactly (best = 98.7 us), plus NT on the colsum W stream.
// NT A/B result (R6): dropping NT on the 512 MB x stream costs ~11 us
// (5.3 vs 6.0 TB/s) -- zero-reuse streams MUST be nontemporal.

#define BATCH   32768
#define HIDDEN  4096
#define INDIM   4096
#define ROWCHUNKS 64
#define ROWS_PER_CHUNK (HIDDEN / ROWCHUNKS)   // 64

typedef float f32x4 __attribute__((ext_vector_type(4)));

// ---------------------------------------------------------------------------
// Kernel 1: partial column sums. grid (4, 64), block 256 -> 256 blocks.
// Thread owns one float4 column-group, sums 64 rows. NT: W is zero-reuse.
__global__ void __launch_bounds__(256)
colsum_partial_kernel(const float* __restrict__ W, float* __restrict__ partial) {
    const int col4 = blockIdx.x * 256 + threadIdx.x;      // 0..1023
    const int row0 = blockIdx.y * ROWS_PER_CHUNK;
    const f32x4* Wv = reinterpret_cast<const f32x4*>(W);
    f32x4 acc = {0.f, 0.f, 0.f, 0.f};
#pragma unroll 16
    for (int r = 0; r < ROWS_PER_CHUNK; ++r) {
        f32x4 v = __builtin_nontemporal_load(&Wv[(size_t)(row0 + r) * (INDIM / 4) + col4]);
        acc += v;
    }
    reinterpret_cast<f32x4*>(partial)[(size_t)blockIdx.y * (INDIM / 4) + col4] = acc;
}

// ---------------------------------------------------------------------------
// Kernel 2 (R4-exact): wide reduce: 64 blocks x 256 threads, block owns 64
// columns. Wave w sums chunks [w*16, (w+1)*16); 1 KiB LDS cross-wave reduce.
__global__ void __launch_bounds__(256)
colsum_final_kernel(const float* __restrict__ partial, float* __restrict__ wsum) {
    __shared__ float red[4][64];
    const int t    = threadIdx.x;
    const int lane = t & 63;
    const int wave = t >> 6;
    const int col  = blockIdx.x * 64 + lane;
    float acc = 0.f;
#pragma unroll
    for (int p = 0; p < ROWCHUNKS / 4; ++p)               // 16 chunks per wave
        acc += partial[(size_t)(wave * (ROWCHUNKS / 4) + p) * INDIM + col];
    red[wave][lane] = acc;
    __syncthreads();
    if (wave == 0)
        wsum[col] = (red[0][lane] + red[1][lane]) + (red[2][lane] + red[3][lane]);
}

// ---------------------------------------------------------------------------
// Kernel 3 (R4-exact): one wave per row, 4 rows/block, 8192 blocks.
// wsum staged in LDS; hot loop issues only NT x loads.
__global__ void __launch_bounds__(256)
matvec_kernel(const float* __restrict__ x, const float* __restrict__ wsum,
              float* __restrict__ out) {
    __shared__ f32x4 wlds[INDIM / 4];                     // 16 KiB
    const int tid = threadIdx.x;
    const f32x4* wv = reinterpret_cast<const f32x4*>(wsum);
#pragma unroll
    for (int j = 0; j < 4; ++j)
        wlds[j * 256 + tid] = wv[j * 256 + tid];
    __syncthreads();

    const int row  = (blockIdx.x * 256 + tid) >> 6;       // global wave id
    const int lane = tid & 63;
    const f32x4* xv = reinterpret_cast<const f32x4*>(x) + (size_t)row * (INDIM / 4);

    float acc = 0.f;
#pragma unroll
    for (int k = 0; k < INDIM / 4 / 64; ++k) {            // 16 steps
        const int idx = k * 64 + lane;
        f32x4 xr = __builtin_nontemporal_load(&xv[idx]);  // zero-reuse stream
        f32x4 wr = wlds[idx];
        acc += xr.x * wr.x + xr.y * wr.y + xr.z * wr.z + xr.w * wr.w;
    }

#pragma unroll
    for (int off = 32; off > 0; off >>= 1)
        acc += __shfl_down(acc, off, 64);

    if (lane == 0)
        out[row] = acc * 1.0f;   // COMBINED_SCALE = 2.0/2.0
}

// ---------------------------------------------------------------------------
extern "C" void kernel_launch(void* const* d_in, const int* in_sizes, int n_in,
                              void* d_out, int out_size, void* d_ws, size_t ws_size,
                              hipStream_t stream) {
    const float* x = (const float*)d_in[0];        // (32768, 4096)
    const float* W = (const float*)d_in[1];        // (4096, 4096)
    float* out = (float*)d_out;                    // 32768 floats

    float* partial = (float*)d_ws;                               // 1 MiB
    float* wsum    = partial + (size_t)ROWCHUNKS * INDIM;        // 16 KiB

    colsum_partial_kernel<<<dim3(INDIM / 4 / 256, ROWCHUNKS), 256, 0, stream>>>(W, partial);
    colsum_final_kernel<<<dim3(INDIM / 64), 256, 0, stream>>>(partial, wsum);
    matvec_kernel<<<dim3(BATCH / 4), 256, 0, stream>>>(x, wsum, out);
}

// Round 9
// 96.583 us; speedup vs baseline: 1.1545x; 1.0205x over previous
//
#include <hip/hip_runtime.h>

// out[b] = sum_h (x @ W^T)[b,h] * 1.0  ==  dot(x[b,:], colsum_h(W))
// R7 base; single change: matvec reads wsum directly through L1 (plain
// cached loads) instead of LDS staging -- no prologue, no barrier.

#define BATCH   32768
#define HIDDEN  4096
#define INDIM   4096
#define ROWCHUNKS 64
#define ROWS_PER_CHUNK (HIDDEN / ROWCHUNKS)   // 64

typedef float f32x4 __attribute__((ext_vector_type(4)));

// ---------------------------------------------------------------------------
// Kernel 1: partial column sums. grid (4, 64), block 256 -> 256 blocks.
__global__ void __launch_bounds__(256)
colsum_partial_kernel(const float* __restrict__ W, float* __restrict__ partial) {
    const int col4 = blockIdx.x * 256 + threadIdx.x;      // 0..1023
    const int row0 = blockIdx.y * ROWS_PER_CHUNK;
    const f32x4* Wv = reinterpret_cast<const f32x4*>(W);
    f32x4 acc = {0.f, 0.f, 0.f, 0.f};
#pragma unroll 16
    for (int r = 0; r < ROWS_PER_CHUNK; ++r) {
        f32x4 v = __builtin_nontemporal_load(&Wv[(size_t)(row0 + r) * (INDIM / 4) + col4]);
        acc += v;
    }
    reinterpret_cast<f32x4*>(partial)[(size_t)blockIdx.y * (INDIM / 4) + col4] = acc;
}

// ---------------------------------------------------------------------------
// Kernel 2 (R7-exact): 64 blocks x 256 threads, block owns 64 columns.
__global__ void __launch_bounds__(256)
colsum_final_kernel(const float* __restrict__ partial, float* __restrict__ wsum) {
    __shared__ float red[4][64];
    const int t    = threadIdx.x;
    const int lane = t & 63;
    const int wave = t >> 6;
    const int col  = blockIdx.x * 64 + lane;
    float acc = 0.f;
#pragma unroll
    for (int p = 0; p < ROWCHUNKS / 4; ++p)               // 16 chunks per wave
        acc += partial[(size_t)(wave * (ROWCHUNKS / 4) + p) * INDIM + col];
    red[wave][lane] = acc;
    __syncthreads();
    if (wave == 0)
        wsum[col] = (red[0][lane] + red[1][lane]) + (red[2][lane] + red[3][lane]);
}

// ---------------------------------------------------------------------------
// Kernel 3: one wave per row, 4 rows/block, 8192 blocks. wsum read directly
// through L1 (16 KiB, hot across all waves of the CU); x via NT stream.
__global__ void __launch_bounds__(256)
matvec_kernel(const float* __restrict__ x, const float* __restrict__ wsum,
              float* __restrict__ out) {
    const int tid  = threadIdx.x;
    const int row  = (blockIdx.x * 256 + tid) >> 6;       // global wave id
    const int lane = tid & 63;
    const f32x4* xv = reinterpret_cast<const f32x4*>(x) + (size_t)row * (INDIM / 4);
    const f32x4* wv = reinterpret_cast<const f32x4*>(wsum);

    float acc = 0.f;
#pragma unroll
    for (int k = 0; k < INDIM / 4 / 64; ++k) {            // 16 steps
        const int idx = k * 64 + lane;
        f32x4 xr = __builtin_nontemporal_load(&xv[idx]);  // zero-reuse stream
        f32x4 wr = wv[idx];                               // cached, L1-hot
        acc += xr.x * wr.x + xr.y * wr.y + xr.z * wr.z + xr.w * wr.w;
    }

#pragma unroll
    for (int off = 32; off > 0; off >>= 1)
        acc += __shfl_down(acc, off, 64);

    if (lane == 0)
        out[row] = acc * 1.0f;   // COMBINED_SCALE = 2.0/2.0
}

// ---------------------------------------------------------------------------
extern "C" void kernel_launch(void* const* d_in, const int* in_sizes, int n_in,
                              void* d_out, int out_size, void* d_ws, size_t ws_size,
                              hipStream_t stream) {
    const float* x = (const float*)d_in[0];        // (32768, 4096)
    const float* W = (const float*)d_in[1];        // (4096, 4096)
    float* out = (float*)d_out;                    // 32768 floats

    float* partial = (float*)d_ws;                               // 1 MiB
    float* wsum    = partial + (size_t)ROWCHUNKS * INDIM;        // 16 KiB

    colsum_partial_kernel<<<dim3(INDIM / 4 / 256, ROWCHUNKS), 256, 0, stream>>>(W, partial);
    colsum_final_kernel<<<dim3(INDIM / 64), 256, 0, stream>>>(partial, wsum);
    matvec_kernel<<<dim3(BATCH / 4), 256, 0, stream>>>(x, wsum, out);
}